// Round 16
// baseline (123.937 us; speedup 1.0000x reference)
//
#include <hip/hip_runtime.h>
#include <hip/hip_fp16.h>

// ---------------------------------------------------------------------------
// TFN-lite layer, MI355X, round 24. Three dispatches:
//   memset(cnt) -> prep_all(table build | geometry scatter) -> tfn_node.
//
//  R24 vs R23 (121.6 us; scatter ~43 us CONSTANT across record size/grid/
//  padding; WRITE_SIZE ~27MB > buffer footprint and payload-independent =>
//  every scattered record costs one PARTIAL 64B line eviction -> masked/RMW
//  HBM write at ~700GB/s effective):
//  * FULL-LINE RECORDS: slot stride 64B; scatter writes the whole line
//    (payload uint4 + 3x zero uint4, 4 consecutive dwordx4 -> write-combine
//    into one fully-dirty line -> clean streaming eviction, no RMW).
//    srec = 102MB ws (fits 256MB). WRITE bytes ~same, at full-line BW.
//  * Node record read: 8B payload at slot*64; +14MB FETCH, hidden by the
//    existing 1-round-ahead record prefetch.
//  * All math verbatim R23 (absmax must stay exactly 0.0625). Padded
//    counters kept (CSTR=16).
// ---------------------------------------------------------------------------

#define INV_S3  0.5773502691896258f   // 1/sqrt(3)
#define A0S     0.1767766952966369f   // 1/sqrt(32)
#define A1S     0.27386127875258306f  // sqrt(3)/sqrt(40)
#define S15     3.872983346207417f    // sqrt(15)
#define S5      2.23606797749979f     // sqrt(5)
#define INV_S10 0.31622776601683794f  // 1/sqrt(10)   (cg121 normalized)
#define INV_S30 0.18257418583505536f  // 1/sqrt(30)

#define TBL   4096
#define RPB   16                      // table rows built per block
#define BBLK  (TBL / RPB)             // 256 build-only blocks
#define GRID  2048
#define DMAX  8.0f
#define CAP   64
#define CSTR  16                      // counter stride (ints) = 64B line
#define RSTR  64                      // record slot stride (bytes) = full line

typedef _Float16 half8 __attribute__((ext_vector_type(8)));
typedef _Float16 half2v __attribute__((ext_vector_type(2)));

// ---------------------------------------------------------------------------
// K1: blocks [0,BBLK) build 16 table rows each; blocks [BBLK,GRID) grid-
// stride the geometry scatter with full-line 64B records.
__global__ __launch_bounds__(256) void prep_all(
    const float* __restrict__ W1, const float* __restrict__ W2,
    const int* __restrict__ ei, const float* __restrict__ pos,
    _Float16* __restrict__ T, int* __restrict__ cnt,
    char* __restrict__ srec, int E) {

    __shared__ float hs[RPB][64];
    int tid = threadIdx.x;
    int wv = tid >> 6, lane = tid & 63;

    if (blockIdx.x < BBLK) {
        // ---------------- build only ----------------
        int jb = blockIdx.x * RPB;
#pragma unroll
        for (int s = 0; s < 4; ++s) {
            int j = jb + wv * 4 + s;
            float d = (float)j * (DMAX / (float)(TBL - 1));
            float acc = 0.f;
#pragma unroll
            for (int i = 0; i < 16; ++i) {
                float t = d - (float)i * (1.0f / 3.0f);
                float r = __expf(-4.5f * t * t);
                acc = fmaf(r, W1[i * 64 + lane], acc);
            }
            hs[wv * 4 + s][lane] = fmaxf(acc, 0.f) * 0.25f;   // /sqrt(16)
        }
        __syncthreads();

        int u = lane >> 3, wo = lane & 7;
        int b0 = u * 16 + wo;
        int b4 = 512 + u * 8 + wo;
        float a0[4] = {0.f, 0.f, 0.f, 0.f};
        float a1[4] = {0.f, 0.f, 0.f, 0.f};
        float a2[4] = {0.f, 0.f, 0.f, 0.f};
        float a3[4] = {0.f, 0.f, 0.f, 0.f};
        float a4[4] = {0.f, 0.f, 0.f, 0.f};
#pragma unroll 2
        for (int k = 0; k < 64; ++k) {
            const float* Wk = W2 + k * 576;
            float w0 = Wk[b0]       + Wk[b0 + 8];
            float w1 = Wk[128 + b0] + Wk[128 + b0 + 8];
            float w2 = Wk[256 + b0] + Wk[256 + b0 + 8];
            float w3 = Wk[384 + b0] + Wk[384 + b0 + 8];
            float w4 = Wk[b4];
#pragma unroll
            for (int s = 0; s < 4; ++s) {
                float hk = hs[wv * 4 + s][k];
                a0[s] = fmaf(hk, w0, a0[s]);
                a1[s] = fmaf(hk, w1, a1[s]);
                a2[s] = fmaf(hk, w2, a2[s]);
                a3[s] = fmaf(hk, w3, a3[s]);
                a4[s] = fmaf(hk, w4, a4[s]);
            }
        }
        // Interleaved pair layout: pair01 at u*16+wo*2, pair23 at +128,
        // w4 at 256+u*8+wo. Row stride 320 halfs (640 B).
#pragma unroll
        for (int s = 0; s < 4; ++s) {
            int j = jb + wv * 4 + s;
            _Float16* Tr = T + (size_t)j * 320;
            int base = u * 16 + wo * 2;
            Tr[base]             = (_Float16)a0[s];
            Tr[base + 1]         = (_Float16)a1[s];
            Tr[128 + base]       = (_Float16)a2[s];
            Tr[128 + base + 1]   = (_Float16)a3[s];
            Tr[256 + u * 8 + wo] = (_Float16)a4[s];
        }
    } else {
        // -------- scatter only (full-line 64B records, no partial evict) ----
        int gtid = (blockIdx.x - BBLK) * 256 + tid;
        int gsz = (GRID - BBLK) * 256;
        for (int e = gtid; e < E; e += gsz) {
            int row = ei[e];
            int col = ei[E + e];
            float ax = pos[3 * row + 0] - pos[3 * col + 0];
            float ay = pos[3 * row + 1] - pos[3 * col + 1];
            float az = pos[3 * row + 2] - pos[3 * col + 2];
            float d2 = ax * ax + ay * ay + az * az + 1e-12f;
            float invd = rsqrtf(d2);
            float dd = d2 * invd;
            int p = atomicAdd(&cnt[(size_t)row * CSTR], 1);
            if (p < CAP) {
                __half2 h0 = __floats2half2_rn(ax * invd, ay * invd);
                __half2 h1 = __floats2half2_rn(az * invd, dd);
                uint4 v;
                v.x = *(const unsigned*)&h0;
                v.y = *(const unsigned*)&h1;
                v.z = 0u; v.w = 0u;
                uint4* slot = (uint4*)(srec + ((size_t)row * CAP + p) * RSTR);
                uint4 z = make_uint4(0u, 0u, 0u, 0u);
                slot[0] = v;          // 4 consecutive dwordx4 = fully-dirty
                slot[1] = z;          // 64B line -> clean streaming eviction
                slot[2] = z;
                slot[3] = z;
            }
        }
    }
}

// ---------------------------------------------------------------------------
// K2: one wave per block (64 thr), block n = node n (R23 verbatim except
// 64B record stride). Nearest-row weights: j0 = round(fj); 5x16B gathers.
__global__ __launch_bounds__(64) void tfn_node(
    const float* __restrict__ x, const char* __restrict__ srec,
    const int* __restrict__ cnt, const _Float16* __restrict__ T,
    float* __restrict__ y, int N) {

    int lane = threadIdx.x & 63;
    int n = blockIdx.x;
    if (n >= N) return;

    int g = lane >> 3;
    int u = lane & 7;
    int kc = cnt[(size_t)n * CSTR];
    if (kc > CAP) kc = CAP;
    const char* recs = srec + (size_t)n * CAP * RSTR;

    const float* xr = x + (size_t)n * 32;
    float xu  = xr[u];
    float xv0 = xr[8 + 3 * u + 0];
    float xv1 = xr[8 + 3 * u + 1];
    float xv2 = xr[8 + 3 * u + 2];
    _Float16 xuh = (_Float16)xu;                    // loop-invariant coefs
    _Float16 p30 = (_Float16)(xv0 * INV_S3);
    _Float16 p31 = (_Float16)(xv1 * INV_S3);
    _Float16 p32 = (_Float16)(xv2 * INV_S3);

    // V: 32 output channels (final layout). V[z]=scalar z; vec w comp k -> V[8+3w+k].
    float V[32];
#pragma unroll
    for (int z = 0; z < 32; ++z) V[z] = 0.f;

    int rounds = (kc + 7) >> 3;
    uint2 rec = make_uint2(0u, 0u);
    if (rounds > 0) rec = *(const uint2*)(recs + (size_t)g * RSTR);
    for (int rd = 0; rd < rounds; ++rd) {
        uint2 cur = rec;
        int slot = rd * 8 + g;
        if (rd + 1 < rounds)                        // prefetch next round
            rec = *(const uint2*)(recs + (size_t)(slot + 8) * RSTR);
        if (slot < kc) {
            __half2 h0 = *(const __half2*)&cur.x;
            __half2 h1 = *(const __half2*)&cur.y;
            float2 f0 = __half22float2(h0);
            float2 f1 = __half22float2(h1);
            float nx = f0.x, ny = f0.y, nz = f1.x;
            float dd = f1.y;

            float fj = dd * ((float)(TBL - 1) / DMAX);
            int j0 = (int)(fj + 0.5f);               // nearest row
            j0 = min(j0, TBL - 1);

            const _Float16* Ar = T + (size_t)j0 * 320;
            const _Float16* Au = Ar + u * 16;
            half8 w01a = *(const half8*)(Au);
            half8 w01b = *(const half8*)(Au + 8);
            half8 w23a = *(const half8*)(Au + 128);
            half8 w23b = *(const half8*)(Au + 136);
            half8 w4l  = *(const half8*)(Ar + 256 + u * 8);

            // geometry (per edge, per u)
            float qu = xv0 * nx + xv1 * ny + xv2 * nz;   // (xv[u].Y1)/S3
            float Y22 = 0.5f * S5 * (3.f * ny * ny - 1.f);
            float Y24 = 0.5f * S15 * (nz * nz - nx * nx);
            float M00 = -Y22 * INV_S30 - Y24 * INV_S10;
            float M11 = 2.f * Y22 * INV_S30;
            float M22 = -Y22 * INV_S30 + Y24 * INV_S10;
            float M01 = (S15 * nx * ny) * INV_S10;
            float M02 = (S15 * nx * nz) * INV_S10;
            float M12 = (S15 * ny * nz) * INV_S10;
            float m0 = M00 * xv0 + M01 * xv1 + M02 * xv2;
            float m1 = M01 * xv0 + M11 * xv1 + M12 * xv2;
            float m2 = M02 * xv0 + M12 * xv1 + M22 * xv2;

            // packed coefficients
            half2v xq;  xq.x = xuh;  xq.y = (_Float16)qu;
            half2v c0;  c0.x = (_Float16)(xu * nx);  c0.y = p30;
            half2v c1;  c1.x = (_Float16)(xu * ny);  c1.y = p31;
            half2v c2;  c2.x = (_Float16)(xu * nz);  c2.y = p32;

            // t0+t1: V[z] += w0*xu + w1*qu   (one dot2 per z)
#pragma unroll
            for (int z = 0; z < 4; ++z) {
                half2v pa; pa.x = w01a[2 * z]; pa.y = w01a[2 * z + 1];
                V[z] = __builtin_amdgcn_fdot2(pa, xq, V[z], false);
                half2v pb; pb.x = w01b[2 * z]; pb.y = w01b[2 * z + 1];
                V[4 + z] = __builtin_amdgcn_fdot2(pb, xq, V[4 + z], false);
            }

            // t2+t3: V[8+3z+k] += w2*(xu*nk) + w3*(xvk/sqrt3)
#pragma unroll
            for (int z = 0; z < 4; ++z) {
                half2v pa; pa.x = w23a[2 * z]; pa.y = w23a[2 * z + 1];
                int b = 8 + 3 * z;
                V[b]     = __builtin_amdgcn_fdot2(pa, c0, V[b],     false);
                V[b + 1] = __builtin_amdgcn_fdot2(pa, c1, V[b + 1], false);
                V[b + 2] = __builtin_amdgcn_fdot2(pa, c2, V[b + 2], false);
                half2v pb; pb.x = w23b[2 * z]; pb.y = w23b[2 * z + 1];
                int b2 = 8 + 3 * (z + 4);
                V[b2]     = __builtin_amdgcn_fdot2(pb, c0, V[b2],     false);
                V[b2 + 1] = __builtin_amdgcn_fdot2(pb, c1, V[b2 + 1], false);
                V[b2 + 2] = __builtin_amdgcn_fdot2(pb, c2, V[b2 + 2], false);
            }

            // t4: f32 (precision-critical path)
#pragma unroll
            for (int z = 0; z < 8; ++z) {
                float we = (float)w4l[z];
                V[8 + 3 * z]  = fmaf(m0, we, V[8 + 3 * z]);
                V[9 + 3 * z]  = fmaf(m1, we, V[9 + 3 * z]);
                V[10 + 3 * z] = fmaf(m2, we, V[10 + 3 * z]);
            }
        }
    }

    // Recursive-halving reduce-scatter over lane bits 4..0 (32 shfls total).
#pragma unroll
    for (int h = 16; h >= 1; h >>= 1) {
        bool hi = (lane & h) != 0;
#pragma unroll
        for (int k = 0; k < h; ++k) {
            float lo = V[k], up = V[k + h];
            float keep = hi ? up : lo;
            float send = hi ? lo : up;
            V[k] = keep + __shfl_xor(send, h, 64);
        }
    }
    V[0] += __shfl_xor(V[0], 32, 64);

    if (lane < 32) {
        float v = V[0] * 0.125f * (lane < 8 ? A0S : A1S);
        if (lane < 8) v = v / (1.0f + __expf(-v));   // silu
        y[(size_t)n * 32 + lane] = v;
    }
}

// ---------------------------------------------------------------------------
extern "C" void kernel_launch(void* const* d_in, const int* in_sizes, int n_in,
                              void* d_out, int out_size, void* d_ws, size_t ws_size,
                              hipStream_t stream) {
    const float* x   = (const float*)d_in[0];
    const float* pos = (const float*)d_in[1];
    const int*   ei  = (const int*)d_in[2];
    const float* W1  = (const float*)d_in[3];
    const float* W2  = (const float*)d_in[4];
    int N = in_sizes[1] / 3;
    int E = in_sizes[2] / 2;

    char* ws = (char*)d_ws;
    size_t off = 0;
    _Float16* T    = (_Float16*)(ws + off); off += (size_t)TBL * 320 * 2;      // 2.62 MB
    int*      cnt  = (int*)(ws + off);      off += (size_t)N * CSTR * 4;       // 1.6 MB
    char*     srec = (char*)(ws + off);     off += (size_t)N * CAP * RSTR;     // 102.4 MB

    float* y = (float*)d_out;

    hipMemsetAsync(cnt, 0, (size_t)N * CSTR * 4, stream);
    hipLaunchKernelGGL(prep_all, dim3(GRID), dim3(256), 0, stream,
                       W1, W2, ei, pos, T, cnt, srec, E);
    hipLaunchKernelGGL(tfn_node, dim3(N), dim3(64), 0, stream,
                       x, srec, cnt, T, y, N);
}

// Round 17
// 121.957 us; speedup vs baseline: 1.0162x; 1.0162x over previous
//
#include <hip/hip_runtime.h>
#include <hip/hip_fp16.h>

// ---------------------------------------------------------------------------
// TFN-lite layer, MI355X, round 25. Three dispatches:
//   memset(cnt) -> prep_all(table build | ILP-split scatter) -> tfn_node.
//
//  R25 vs R23/R24 (121.6/123.9 us; scatter ~43 us constant under FIVE
//  variations -- record size, grid, counter padding, role split, full-line
//  writes (R24: 1.55x write bytes at same time => writes exonerated)):
//  Remaining suspects: far-atomic throughput (~9.3/ns) vs per-edge serial
//  LATENCY with no ILP (0.87 edges/thread => one dependent chain per thread,
//  nothing overlaps). Discriminating experiment:
//  * ILP-SPLIT SCATTER: 512 scatter blocks, 4 edges/thread, two unrolled
//    passes: A) 4x {ei loads, atomicAdd} -- atomic latencies 4-way in
//    flight; B) 4x {pos gathers, geometry, 8B store} -- no atomic in chain.
//    Same atomic count, same stores, same math (bucket order changes; the
//    set and kc are identical -- order was never deterministic).
//  * Records back to R23's 8B (R24's 64B lines cost +2.4 us). CSTR=16 kept.
//  * If prep drops: latency-bound confirmed, iterate. If ~43: atomic HW
//    ceiling confirmed -> structural roofline (fill 43 + atomics 43 +
//    node 35 = measured 121.6).
// ---------------------------------------------------------------------------

#define INV_S3  0.5773502691896258f   // 1/sqrt(3)
#define A0S     0.1767766952966369f   // 1/sqrt(32)
#define A1S     0.27386127875258306f  // sqrt(3)/sqrt(40)
#define S15     3.872983346207417f    // sqrt(15)
#define S5      2.23606797749979f     // sqrt(5)
#define INV_S10 0.31622776601683794f  // 1/sqrt(10)   (cg121 normalized)
#define INV_S30 0.18257418583505536f  // 1/sqrt(30)

#define TBL   4096
#define RPB   16                      // table rows built per block
#define BBLK  (TBL / RPB)             // 256 build-only blocks
#define SBLK  512                     // scatter blocks
#define UNR   4                       // edges per scatter thread
#define DMAX  8.0f
#define CAP   64
#define CSTR  16                      // counter stride (ints) = 64B line

typedef _Float16 half8 __attribute__((ext_vector_type(8)));
typedef _Float16 half2v __attribute__((ext_vector_type(2)));

// ---------------------------------------------------------------------------
// K1: blocks [0,BBLK) build 16 table rows each; blocks [BBLK,BBLK+SBLK)
// run the ILP-split scatter (4 edges/thread, atomics batched first).
__global__ __launch_bounds__(256) void prep_all(
    const float* __restrict__ W1, const float* __restrict__ W2,
    const int* __restrict__ ei, const float* __restrict__ pos,
    _Float16* __restrict__ T, int* __restrict__ cnt,
    uint2* __restrict__ srec, int E) {

    __shared__ float hs[RPB][64];
    int tid = threadIdx.x;
    int wv = tid >> 6, lane = tid & 63;

    if (blockIdx.x < BBLK) {
        // ---------------- build only ----------------
        int jb = blockIdx.x * RPB;
#pragma unroll
        for (int s = 0; s < 4; ++s) {
            int j = jb + wv * 4 + s;
            float d = (float)j * (DMAX / (float)(TBL - 1));
            float acc = 0.f;
#pragma unroll
            for (int i = 0; i < 16; ++i) {
                float t = d - (float)i * (1.0f / 3.0f);
                float r = __expf(-4.5f * t * t);
                acc = fmaf(r, W1[i * 64 + lane], acc);
            }
            hs[wv * 4 + s][lane] = fmaxf(acc, 0.f) * 0.25f;   // /sqrt(16)
        }
        __syncthreads();

        int u = lane >> 3, wo = lane & 7;
        int b0 = u * 16 + wo;
        int b4 = 512 + u * 8 + wo;
        float a0[4] = {0.f, 0.f, 0.f, 0.f};
        float a1[4] = {0.f, 0.f, 0.f, 0.f};
        float a2[4] = {0.f, 0.f, 0.f, 0.f};
        float a3[4] = {0.f, 0.f, 0.f, 0.f};
        float a4[4] = {0.f, 0.f, 0.f, 0.f};
#pragma unroll 2
        for (int k = 0; k < 64; ++k) {
            const float* Wk = W2 + k * 576;
            float w0 = Wk[b0]       + Wk[b0 + 8];
            float w1 = Wk[128 + b0] + Wk[128 + b0 + 8];
            float w2 = Wk[256 + b0] + Wk[256 + b0 + 8];
            float w3 = Wk[384 + b0] + Wk[384 + b0 + 8];
            float w4 = Wk[b4];
#pragma unroll
            for (int s = 0; s < 4; ++s) {
                float hk = hs[wv * 4 + s][k];
                a0[s] = fmaf(hk, w0, a0[s]);
                a1[s] = fmaf(hk, w1, a1[s]);
                a2[s] = fmaf(hk, w2, a2[s]);
                a3[s] = fmaf(hk, w3, a3[s]);
                a4[s] = fmaf(hk, w4, a4[s]);
            }
        }
        // Interleaved pair layout: pair01 at u*16+wo*2, pair23 at +128,
        // w4 at 256+u*8+wo. Row stride 320 halfs (640 B).
#pragma unroll
        for (int s = 0; s < 4; ++s) {
            int j = jb + wv * 4 + s;
            _Float16* Tr = T + (size_t)j * 320;
            int base = u * 16 + wo * 2;
            Tr[base]             = (_Float16)a0[s];
            Tr[base + 1]         = (_Float16)a1[s];
            Tr[128 + base]       = (_Float16)a2[s];
            Tr[128 + base + 1]   = (_Float16)a3[s];
            Tr[256 + u * 8 + wo] = (_Float16)a4[s];
        }
    } else {
        // ------- ILP-split scatter: pass A atomics, pass B geometry -------
        int tid0 = (blockIdx.x - BBLK) * 256 + tid;
        const int stride = SBLK * 256;

        int row[UNR], col[UNR], p[UNR];
#pragma unroll
        for (int i = 0; i < UNR; ++i) {
            int e = tid0 + i * stride;
            row[i] = 0; col[i] = 0; p[i] = CAP;      // invalid -> skip in B
            if (e < E) {
                row[i] = ei[e];
                col[i] = ei[E + e];
                p[i] = atomicAdd(&cnt[(size_t)row[i] * CSTR], 1);
            }
        }
#pragma unroll
        for (int i = 0; i < UNR; ++i) {
            if (p[i] < CAP) {
                float ax = pos[3 * row[i] + 0] - pos[3 * col[i] + 0];
                float ay = pos[3 * row[i] + 1] - pos[3 * col[i] + 1];
                float az = pos[3 * row[i] + 2] - pos[3 * col[i] + 2];
                float d2 = ax * ax + ay * ay + az * az + 1e-12f;
                float invd = rsqrtf(d2);
                float dd = d2 * invd;
                __half2 h0 = __floats2half2_rn(ax * invd, ay * invd);
                __half2 h1 = __floats2half2_rn(az * invd, dd);
                uint2 r;
                r.x = *(const unsigned*)&h0;
                r.y = *(const unsigned*)&h1;
                srec[(size_t)row[i] * CAP + p[i]] = r;
            }
        }
    }
}

// ---------------------------------------------------------------------------
// K2: one wave per block (64 thr), block n = node n (R23 verbatim).
// Nearest-row weights: j0 = round(fj); 5x16B gathers per edge-lane, no lerp.
__global__ __launch_bounds__(64) void tfn_node(
    const float* __restrict__ x, const uint2* __restrict__ srec,
    const int* __restrict__ cnt, const _Float16* __restrict__ T,
    float* __restrict__ y, int N) {

    int lane = threadIdx.x & 63;
    int n = blockIdx.x;
    if (n >= N) return;

    int g = lane >> 3;
    int u = lane & 7;
    int kc = cnt[(size_t)n * CSTR];
    if (kc > CAP) kc = CAP;
    const uint2* recs = srec + (size_t)n * CAP;

    const float* xr = x + (size_t)n * 32;
    float xu  = xr[u];
    float xv0 = xr[8 + 3 * u + 0];
    float xv1 = xr[8 + 3 * u + 1];
    float xv2 = xr[8 + 3 * u + 2];
    _Float16 xuh = (_Float16)xu;                    // loop-invariant coefs
    _Float16 p30 = (_Float16)(xv0 * INV_S3);
    _Float16 p31 = (_Float16)(xv1 * INV_S3);
    _Float16 p32 = (_Float16)(xv2 * INV_S3);

    // V: 32 output channels (final layout). V[z]=scalar z; vec w comp k -> V[8+3w+k].
    float V[32];
#pragma unroll
    for (int z = 0; z < 32; ++z) V[z] = 0.f;

    int rounds = (kc + 7) >> 3;
    uint2 rec = make_uint2(0u, 0u);
    if (rounds > 0) rec = recs[g];      // always-safe: CAP slots allocated
    for (int rd = 0; rd < rounds; ++rd) {
        uint2 cur = rec;
        int slot = rd * 8 + g;
        if (rd + 1 < rounds) rec = recs[slot + 8];   // prefetch next round
        if (slot < kc) {
            __half2 h0 = *(const __half2*)&cur.x;
            __half2 h1 = *(const __half2*)&cur.y;
            float2 f0 = __half22float2(h0);
            float2 f1 = __half22float2(h1);
            float nx = f0.x, ny = f0.y, nz = f1.x;
            float dd = f1.y;

            float fj = dd * ((float)(TBL - 1) / DMAX);
            int j0 = (int)(fj + 0.5f);               // nearest row
            j0 = min(j0, TBL - 1);

            const _Float16* Ar = T + (size_t)j0 * 320;
            const _Float16* Au = Ar + u * 16;
            half8 w01a = *(const half8*)(Au);
            half8 w01b = *(const half8*)(Au + 8);
            half8 w23a = *(const half8*)(Au + 128);
            half8 w23b = *(const half8*)(Au + 136);
            half8 w4l  = *(const half8*)(Ar + 256 + u * 8);

            // geometry (per edge, per u)
            float qu = xv0 * nx + xv1 * ny + xv2 * nz;   // (xv[u].Y1)/S3
            float Y22 = 0.5f * S5 * (3.f * ny * ny - 1.f);
            float Y24 = 0.5f * S15 * (nz * nz - nx * nx);
            float M00 = -Y22 * INV_S30 - Y24 * INV_S10;
            float M11 = 2.f * Y22 * INV_S30;
            float M22 = -Y22 * INV_S30 + Y24 * INV_S10;
            float M01 = (S15 * nx * ny) * INV_S10;
            float M02 = (S15 * nx * nz) * INV_S10;
            float M12 = (S15 * ny * nz) * INV_S10;
            float m0 = M00 * xv0 + M01 * xv1 + M02 * xv2;
            float m1 = M01 * xv0 + M11 * xv1 + M12 * xv2;
            float m2 = M02 * xv0 + M12 * xv1 + M22 * xv2;

            // packed coefficients
            half2v xq;  xq.x = xuh;  xq.y = (_Float16)qu;
            half2v c0;  c0.x = (_Float16)(xu * nx);  c0.y = p30;
            half2v c1;  c1.x = (_Float16)(xu * ny);  c1.y = p31;
            half2v c2;  c2.x = (_Float16)(xu * nz);  c2.y = p32;

            // t0+t1: V[z] += w0*xu + w1*qu   (one dot2 per z)
#pragma unroll
            for (int z = 0; z < 4; ++z) {
                half2v pa; pa.x = w01a[2 * z]; pa.y = w01a[2 * z + 1];
                V[z] = __builtin_amdgcn_fdot2(pa, xq, V[z], false);
                half2v pb; pb.x = w01b[2 * z]; pb.y = w01b[2 * z + 1];
                V[4 + z] = __builtin_amdgcn_fdot2(pb, xq, V[4 + z], false);
            }

            // t2+t3: V[8+3z+k] += w2*(xu*nk) + w3*(xvk/sqrt3)
#pragma unroll
            for (int z = 0; z < 4; ++z) {
                half2v pa; pa.x = w23a[2 * z]; pa.y = w23a[2 * z + 1];
                int b = 8 + 3 * z;
                V[b]     = __builtin_amdgcn_fdot2(pa, c0, V[b],     false);
                V[b + 1] = __builtin_amdgcn_fdot2(pa, c1, V[b + 1], false);
                V[b + 2] = __builtin_amdgcn_fdot2(pa, c2, V[b + 2], false);
                half2v pb; pb.x = w23b[2 * z]; pb.y = w23b[2 * z + 1];
                int b2 = 8 + 3 * (z + 4);
                V[b2]     = __builtin_amdgcn_fdot2(pb, c0, V[b2],     false);
                V[b2 + 1] = __builtin_amdgcn_fdot2(pb, c1, V[b2 + 1], false);
                V[b2 + 2] = __builtin_amdgcn_fdot2(pb, c2, V[b2 + 2], false);
            }

            // t4: f32 (precision-critical path)
#pragma unroll
            for (int z = 0; z < 8; ++z) {
                float we = (float)w4l[z];
                V[8 + 3 * z]  = fmaf(m0, we, V[8 + 3 * z]);
                V[9 + 3 * z]  = fmaf(m1, we, V[9 + 3 * z]);
                V[10 + 3 * z] = fmaf(m2, we, V[10 + 3 * z]);
            }
        }
    }

    // Recursive-halving reduce-scatter over lane bits 4..0 (32 shfls total).
#pragma unroll
    for (int h = 16; h >= 1; h >>= 1) {
        bool hi = (lane & h) != 0;
#pragma unroll
        for (int k = 0; k < h; ++k) {
            float lo = V[k], up = V[k + h];
            float keep = hi ? up : lo;
            float send = hi ? lo : up;
            V[k] = keep + __shfl_xor(send, h, 64);
        }
    }
    V[0] += __shfl_xor(V[0], 32, 64);

    if (lane < 32) {
        float v = V[0] * 0.125f * (lane < 8 ? A0S : A1S);
        if (lane < 8) v = v / (1.0f + __expf(-v));   // silu
        y[(size_t)n * 32 + lane] = v;
    }
}

// ---------------------------------------------------------------------------
extern "C" void kernel_launch(void* const* d_in, const int* in_sizes, int n_in,
                              void* d_out, int out_size, void* d_ws, size_t ws_size,
                              hipStream_t stream) {
    const float* x   = (const float*)d_in[0];
    const float* pos = (const float*)d_in[1];
    const int*   ei  = (const int*)d_in[2];
    const float* W1  = (const float*)d_in[3];
    const float* W2  = (const float*)d_in[4];
    int N = in_sizes[1] / 3;
    int E = in_sizes[2] / 2;

    char* ws = (char*)d_ws;
    size_t off = 0;
    _Float16* T    = (_Float16*)(ws + off); off += (size_t)TBL * 320 * 2;      // 2.62 MB
    int*      cnt  = (int*)(ws + off);      off += (size_t)N * CSTR * 4;       // 1.6 MB
    uint2*    srec = (uint2*)(ws + off);    off += (size_t)N * CAP * 8;        // 12.8 MB

    float* y = (float*)d_out;

    hipMemsetAsync(cnt, 0, (size_t)N * CSTR * 4, stream);
    hipLaunchKernelGGL(prep_all, dim3(BBLK + SBLK), dim3(256), 0, stream,
                       W1, W2, ei, pos, T, cnt, srec, E);
    hipLaunchKernelGGL(tfn_node, dim3(N), dim3(64), 0, stream,
                       x, srec, cnt, T, y, N);
}

// Round 18
// 121.731 us; speedup vs baseline: 1.0181x; 1.0019x over previous
//
#include <hip/hip_runtime.h>
#include <hip/hip_fp16.h>

// ---------------------------------------------------------------------------
// TFN-lite layer, MI355X, round 26. FOUR dispatches, software-pipelined
// halves (NH = N/2):
//   memset(cnt)
//   K1 prep_A   : table build | scatter edges with row <  NH
//   K2 scat_node: scatter edges with row >= NH  ||  node blocks rows < NH
//   K3 node_B   : node blocks rows >= NH
//
//  R26 vs R25 (122.0 us; scatter ~44 us invariant to payload/full-line/
//  padding/grid/ILP -> ~9 ops/ns throughput wall; accounting closes:
//  fill 43 + prep 44 + node 34 + memset = 122):
//  * PIPELINE THE HALVES: node[0,NH) only needs scatter of rows < NH, so
//    scatter-B and node-A co-run in ONE dispatch (disjoint row ranges, no
//    intra-dispatch dep; scatter = atomic-unit-bound, node = latency-bound
//    -> orthogonal resources). Critical path 22+max(22,18)+18 ~ 64 us of
//    GPU work vs 79 serialized. Wins under BOTH surviving scatter theories
//    (time scales with edge count for throughput- AND latency-bound).
//  * All math verbatim R23/R25 (8B records, CSTR=16, TBL=4096 nearest-row).
// ---------------------------------------------------------------------------

#define INV_S3  0.5773502691896258f   // 1/sqrt(3)
#define A0S     0.1767766952966369f   // 1/sqrt(32)
#define A1S     0.27386127875258306f  // sqrt(3)/sqrt(40)
#define S15     3.872983346207417f    // sqrt(15)
#define S5      2.23606797749979f     // sqrt(5)
#define INV_S10 0.31622776601683794f  // 1/sqrt(10)   (cg121 normalized)
#define INV_S30 0.18257418583505536f  // 1/sqrt(30)

#define TBL   4096
#define RPB   16                      // table rows built per block
#define BBLK  (TBL / RPB)             // 256 build-only blocks
#define SBLK1 1024                    // K1 scatter blocks (256 thr)
#define SBLK2 2048                    // K2 scatter blocks (64 thr)
#define DMAX  8.0f
#define CAP   64
#define CSTR  16                      // counter stride (ints) = 64B line

typedef _Float16 half8 __attribute__((ext_vector_type(8)));
typedef _Float16 half2v __attribute__((ext_vector_type(2)));

// ---------------------------------------------------------------------------
// shared scatter body: process edge e if its row is in [lo, hi)
__device__ __forceinline__ void scatter_edge(
    int e, int lo, int hi, const int* __restrict__ ei,
    const float* __restrict__ pos, int* __restrict__ cnt,
    uint2* __restrict__ srec, int E) {
    int row = ei[e];
    if (row >= lo && row < hi) {
        int col = ei[E + e];
        float ax = pos[3 * row + 0] - pos[3 * col + 0];
        float ay = pos[3 * row + 1] - pos[3 * col + 1];
        float az = pos[3 * row + 2] - pos[3 * col + 2];
        float d2 = ax * ax + ay * ay + az * az + 1e-12f;
        float invd = rsqrtf(d2);
        float dd = d2 * invd;
        int p = atomicAdd(&cnt[(size_t)row * CSTR], 1);
        if (p < CAP) {
            __half2 h0 = __floats2half2_rn(ax * invd, ay * invd);
            __half2 h1 = __floats2half2_rn(az * invd, dd);
            uint2 r;
            r.x = *(const unsigned*)&h0;
            r.y = *(const unsigned*)&h1;
            srec[(size_t)row * CAP + p] = r;
        }
    }
}

// ---------------------------------------------------------------------------
// shared node body (R23 verbatim): one 64-lane wave computes node n.
__device__ __forceinline__ void node_body(
    int n, int lane, const float* __restrict__ x,
    const uint2* __restrict__ srec, const int* __restrict__ cnt,
    const _Float16* __restrict__ T, float* __restrict__ y) {

    int g = lane >> 3;
    int u = lane & 7;
    int kc = cnt[(size_t)n * CSTR];
    if (kc > CAP) kc = CAP;
    const uint2* recs = srec + (size_t)n * CAP;

    const float* xr = x + (size_t)n * 32;
    float xu  = xr[u];
    float xv0 = xr[8 + 3 * u + 0];
    float xv1 = xr[8 + 3 * u + 1];
    float xv2 = xr[8 + 3 * u + 2];
    _Float16 xuh = (_Float16)xu;                    // loop-invariant coefs
    _Float16 p30 = (_Float16)(xv0 * INV_S3);
    _Float16 p31 = (_Float16)(xv1 * INV_S3);
    _Float16 p32 = (_Float16)(xv2 * INV_S3);

    float V[32];
#pragma unroll
    for (int z = 0; z < 32; ++z) V[z] = 0.f;

    int rounds = (kc + 7) >> 3;
    uint2 rec = make_uint2(0u, 0u);
    if (rounds > 0) rec = recs[g];      // always-safe: CAP slots allocated
    for (int rd = 0; rd < rounds; ++rd) {
        uint2 cur = rec;
        int slot = rd * 8 + g;
        if (rd + 1 < rounds) rec = recs[slot + 8];   // prefetch next round
        if (slot < kc) {
            __half2 h0 = *(const __half2*)&cur.x;
            __half2 h1 = *(const __half2*)&cur.y;
            float2 f0 = __half22float2(h0);
            float2 f1 = __half22float2(h1);
            float nx = f0.x, ny = f0.y, nz = f1.x;
            float dd = f1.y;

            float fj = dd * ((float)(TBL - 1) / DMAX);
            int j0 = (int)(fj + 0.5f);               // nearest row
            j0 = min(j0, TBL - 1);

            const _Float16* Ar = T + (size_t)j0 * 320;
            const _Float16* Au = Ar + u * 16;
            half8 w01a = *(const half8*)(Au);
            half8 w01b = *(const half8*)(Au + 8);
            half8 w23a = *(const half8*)(Au + 128);
            half8 w23b = *(const half8*)(Au + 136);
            half8 w4l  = *(const half8*)(Ar + 256 + u * 8);

            // geometry (per edge, per u)
            float qu = xv0 * nx + xv1 * ny + xv2 * nz;   // (xv[u].Y1)/S3
            float Y22 = 0.5f * S5 * (3.f * ny * ny - 1.f);
            float Y24 = 0.5f * S15 * (nz * nz - nx * nx);
            float M00 = -Y22 * INV_S30 - Y24 * INV_S10;
            float M11 = 2.f * Y22 * INV_S30;
            float M22 = -Y22 * INV_S30 + Y24 * INV_S10;
            float M01 = (S15 * nx * ny) * INV_S10;
            float M02 = (S15 * nx * nz) * INV_S10;
            float M12 = (S15 * ny * nz) * INV_S10;
            float m0 = M00 * xv0 + M01 * xv1 + M02 * xv2;
            float m1 = M01 * xv0 + M11 * xv1 + M12 * xv2;
            float m2 = M02 * xv0 + M12 * xv1 + M22 * xv2;

            // packed coefficients
            half2v xq;  xq.x = xuh;  xq.y = (_Float16)qu;
            half2v c0;  c0.x = (_Float16)(xu * nx);  c0.y = p30;
            half2v c1;  c1.x = (_Float16)(xu * ny);  c1.y = p31;
            half2v c2;  c2.x = (_Float16)(xu * nz);  c2.y = p32;

            // t0+t1: V[z] += w0*xu + w1*qu   (one dot2 per z)
#pragma unroll
            for (int z = 0; z < 4; ++z) {
                half2v pa; pa.x = w01a[2 * z]; pa.y = w01a[2 * z + 1];
                V[z] = __builtin_amdgcn_fdot2(pa, xq, V[z], false);
                half2v pb; pb.x = w01b[2 * z]; pb.y = w01b[2 * z + 1];
                V[4 + z] = __builtin_amdgcn_fdot2(pb, xq, V[4 + z], false);
            }

            // t2+t3: V[8+3z+k] += w2*(xu*nk) + w3*(xvk/sqrt3)
#pragma unroll
            for (int z = 0; z < 4; ++z) {
                half2v pa; pa.x = w23a[2 * z]; pa.y = w23a[2 * z + 1];
                int b = 8 + 3 * z;
                V[b]     = __builtin_amdgcn_fdot2(pa, c0, V[b],     false);
                V[b + 1] = __builtin_amdgcn_fdot2(pa, c1, V[b + 1], false);
                V[b + 2] = __builtin_amdgcn_fdot2(pa, c2, V[b + 2], false);
                half2v pb; pb.x = w23b[2 * z]; pb.y = w23b[2 * z + 1];
                int b2 = 8 + 3 * (z + 4);
                V[b2]     = __builtin_amdgcn_fdot2(pb, c0, V[b2],     false);
                V[b2 + 1] = __builtin_amdgcn_fdot2(pb, c1, V[b2 + 1], false);
                V[b2 + 2] = __builtin_amdgcn_fdot2(pb, c2, V[b2 + 2], false);
            }

            // t4: f32 (precision-critical path)
#pragma unroll
            for (int z = 0; z < 8; ++z) {
                float we = (float)w4l[z];
                V[8 + 3 * z]  = fmaf(m0, we, V[8 + 3 * z]);
                V[9 + 3 * z]  = fmaf(m1, we, V[9 + 3 * z]);
                V[10 + 3 * z] = fmaf(m2, we, V[10 + 3 * z]);
            }
        }
    }

    // Recursive-halving reduce-scatter over lane bits 4..0 (32 shfls total).
#pragma unroll
    for (int h = 16; h >= 1; h >>= 1) {
        bool hi = (lane & h) != 0;
#pragma unroll
        for (int k = 0; k < h; ++k) {
            float lo = V[k], up = V[k + h];
            float keep = hi ? up : lo;
            float send = hi ? lo : up;
            V[k] = keep + __shfl_xor(send, h, 64);
        }
    }
    V[0] += __shfl_xor(V[0], 32, 64);

    if (lane < 32) {
        float v = V[0] * 0.125f * (lane < 8 ? A0S : A1S);
        if (lane < 8) v = v / (1.0f + __expf(-v));   // silu
        y[(size_t)n * 32 + lane] = v;
    }
}

// ---------------------------------------------------------------------------
// K1: blocks [0,BBLK) build the table; blocks [BBLK,BBLK+SBLK1) scatter
// edges with row < NH.
__global__ __launch_bounds__(256) void prep_A(
    const float* __restrict__ W1, const float* __restrict__ W2,
    const int* __restrict__ ei, const float* __restrict__ pos,
    _Float16* __restrict__ T, int* __restrict__ cnt,
    uint2* __restrict__ srec, int E, int NH) {

    __shared__ float hs[RPB][64];
    int tid = threadIdx.x;
    int wv = tid >> 6, lane = tid & 63;

    if (blockIdx.x < BBLK) {
        // ---------------- build only ----------------
        int jb = blockIdx.x * RPB;
#pragma unroll
        for (int s = 0; s < 4; ++s) {
            int j = jb + wv * 4 + s;
            float d = (float)j * (DMAX / (float)(TBL - 1));
            float acc = 0.f;
#pragma unroll
            for (int i = 0; i < 16; ++i) {
                float t = d - (float)i * (1.0f / 3.0f);
                float r = __expf(-4.5f * t * t);
                acc = fmaf(r, W1[i * 64 + lane], acc);
            }
            hs[wv * 4 + s][lane] = fmaxf(acc, 0.f) * 0.25f;   // /sqrt(16)
        }
        __syncthreads();

        int u = lane >> 3, wo = lane & 7;
        int b0 = u * 16 + wo;
        int b4 = 512 + u * 8 + wo;
        float a0[4] = {0.f, 0.f, 0.f, 0.f};
        float a1[4] = {0.f, 0.f, 0.f, 0.f};
        float a2[4] = {0.f, 0.f, 0.f, 0.f};
        float a3[4] = {0.f, 0.f, 0.f, 0.f};
        float a4[4] = {0.f, 0.f, 0.f, 0.f};
#pragma unroll 2
        for (int k = 0; k < 64; ++k) {
            const float* Wk = W2 + k * 576;
            float w0 = Wk[b0]       + Wk[b0 + 8];
            float w1 = Wk[128 + b0] + Wk[128 + b0 + 8];
            float w2 = Wk[256 + b0] + Wk[256 + b0 + 8];
            float w3 = Wk[384 + b0] + Wk[384 + b0 + 8];
            float w4 = Wk[b4];
#pragma unroll
            for (int s = 0; s < 4; ++s) {
                float hk = hs[wv * 4 + s][k];
                a0[s] = fmaf(hk, w0, a0[s]);
                a1[s] = fmaf(hk, w1, a1[s]);
                a2[s] = fmaf(hk, w2, a2[s]);
                a3[s] = fmaf(hk, w3, a3[s]);
                a4[s] = fmaf(hk, w4, a4[s]);
            }
        }
        // Interleaved pair layout: pair01 at u*16+wo*2, pair23 at +128,
        // w4 at 256+u*8+wo. Row stride 320 halfs (640 B).
#pragma unroll
        for (int s = 0; s < 4; ++s) {
            int j = jb + wv * 4 + s;
            _Float16* Tr = T + (size_t)j * 320;
            int base = u * 16 + wo * 2;
            Tr[base]             = (_Float16)a0[s];
            Tr[base + 1]         = (_Float16)a1[s];
            Tr[128 + base]       = (_Float16)a2[s];
            Tr[128 + base + 1]   = (_Float16)a3[s];
            Tr[256 + u * 8 + wo] = (_Float16)a4[s];
        }
    } else {
        // -------- scatter half A: rows [0, NH) --------
        int gtid = (blockIdx.x - BBLK) * 256 + tid;
        int gsz = SBLK1 * 256;
        for (int e = gtid; e < E; e += gsz)
            scatter_edge(e, 0, NH, ei, pos, cnt, srec, E);
    }
}

// ---------------------------------------------------------------------------
// K2: blocks [0,SBLK2) scatter rows >= NH; blocks [SBLK2, SBLK2+NH) run
// node n = blockIdx - SBLK2 (rows < NH -- their buckets completed in K1).
__global__ __launch_bounds__(64) void scat_node(
    const float* __restrict__ x, const float* __restrict__ pos,
    const int* __restrict__ ei, _Float16* __restrict__ T,
    int* __restrict__ cnt, uint2* __restrict__ srec,
    float* __restrict__ y, int E, int N, int NH) {

    int lane = threadIdx.x & 63;
    if (blockIdx.x < SBLK2) {
        int gtid = blockIdx.x * 64 + lane;
        const int gsz = SBLK2 * 64;
        for (int e = gtid; e < E; e += gsz)
            scatter_edge(e, NH, N, ei, pos, cnt, srec, E);
    } else {
        int n = blockIdx.x - SBLK2;          // n in [0, NH)
        node_body(n, lane, x, srec, cnt, T, y);
    }
}

// ---------------------------------------------------------------------------
// K3: node blocks for rows [NH, N).
__global__ __launch_bounds__(64) void node_B(
    const float* __restrict__ x, const uint2* __restrict__ srec,
    const int* __restrict__ cnt, const _Float16* __restrict__ T,
    float* __restrict__ y, int N, int NH) {

    int lane = threadIdx.x & 63;
    int n = NH + blockIdx.x;
    if (n >= N) return;
    node_body(n, lane, x, srec, cnt, T, y);
}

// ---------------------------------------------------------------------------
extern "C" void kernel_launch(void* const* d_in, const int* in_sizes, int n_in,
                              void* d_out, int out_size, void* d_ws, size_t ws_size,
                              hipStream_t stream) {
    const float* x   = (const float*)d_in[0];
    const float* pos = (const float*)d_in[1];
    const int*   ei  = (const int*)d_in[2];
    const float* W1  = (const float*)d_in[3];
    const float* W2  = (const float*)d_in[4];
    int N = in_sizes[1] / 3;
    int E = in_sizes[2] / 2;
    int NH = (N + 1) / 2;

    char* ws = (char*)d_ws;
    size_t off = 0;
    _Float16* T    = (_Float16*)(ws + off); off += (size_t)TBL * 320 * 2;      // 2.62 MB
    int*      cnt  = (int*)(ws + off);      off += (size_t)N * CSTR * 4;       // 1.6 MB
    uint2*    srec = (uint2*)(ws + off);    off += (size_t)N * CAP * 8;        // 12.8 MB

    float* y = (float*)d_out;

    hipMemsetAsync(cnt, 0, (size_t)N * CSTR * 4, stream);
    hipLaunchKernelGGL(prep_A, dim3(BBLK + SBLK1), dim3(256), 0, stream,
                       W1, W2, ei, pos, T, cnt, srec, E, NH);
    hipLaunchKernelGGL(scat_node, dim3(SBLK2 + NH), dim3(64), 0, stream,
                       x, pos, ei, T, cnt, srec, y, E, N, NH);
    hipLaunchKernelGGL(node_B, dim3(N - NH), dim3(64), 0, stream,
                       x, srec, cnt, T, y, N, NH);
}